// Round 5
// baseline (626.194 us; speedup 1.0000x reference)
//
#include <hip/hip_runtime.h>
#include <hip/hip_bf16.h>

typedef __bf16 bf16x8 __attribute__((ext_vector_type(8)));
typedef __bf16 bf16x4 __attribute__((ext_vector_type(4)));
typedef float f32x4 __attribute__((ext_vector_type(4)));

#define NEG_INF (-__builtin_inff())

// ---------------------------------------------------------------------------
// f32 -> bf16 conversion (vectorized, grid-stride)
// ---------------------------------------------------------------------------
__global__ void cvt_f32_bf16(const float* __restrict__ src, __bf16* __restrict__ dst, int n) {
    int idx = blockIdx.x * blockDim.x + threadIdx.x;
    int stride = gridDim.x * blockDim.x;
    for (int i = idx * 4; i < n; i += stride * 4) {
        float4 v = *(const float4*)(src + i);
        bf16x4 o;
        o[0] = (__bf16)v.x; o[1] = (__bf16)v.y; o[2] = (__bf16)v.z; o[3] = (__bf16)v.w;
        *(bf16x4*)(dst + i) = o;
    }
}

// ---------------------------------------------------------------------------
// QKV GEMM: 256x128 tile, BK=64, 512 threads (8 waves as 4m x 2n),
// single-buffer linear LDS (A 256x64 = 32KB | B 128x64 = 16KB), staged by
// global_load_lds width=16, 2 barriers per K-step (m97 schedule).
// out scattered to QKV layout; Q scaled 1/8; V transposed to [bh][d][2048].
// Grid 768 blocks = exactly 3/CU, one round.
// ---------------------------------------------------------------------------
__launch_bounds__(512, 6)
__global__ void gemm_qkv(const __bf16* __restrict__ A, const __bf16* __restrict__ Bm,
                         __bf16* __restrict__ Out, int M, int N, int K) {
    __shared__ __align__(1024) char smem[49152];   // A [256][64] | B [128][64]
    const int tid = threadIdx.x;
    const int w = tid >> 6, lane = tid & 63;
    const int lr = lane & 15, lg = lane >> 4;
    const int wm0 = (w >> 1) * 64, wn0 = (w & 1) * 64;

    // bijective XCD swizzle (768 % 8 == 0)
    const int nbx = 24;                       // N/128
    int id = blockIdx.x;
    int q8 = (int)(gridDim.x) >> 3;
    int vid = (id & 7) * q8 + (id >> 3);
    const int m0 = (vid / nbx) * 256, n0 = (vid % nbx) * 128;

    const char* Ab = (const char*)A;
    const char* Bb = (const char*)Bm;

    f32x4 acc[4][4] = {};

    const int s_row8 = lane >> 3;   // 0..7
    const int s_col16 = lane & 7;   // 0..7

    const int nt = K >> 6;          // 16
    for (int t = 0; t < nt; ++t) {
        // stage 48KB: 48 chunks of 1KB; wave w covers chunks 6w..6w+5
#pragma unroll
        for (int i = 0; i < 6; ++i) {
            int c = w * 6 + i;                       // wave-uniform 0..47
            const char* src;
            if (c < 32) {                            // A chunk: rows c*8..c*8+7
                int row = c * 8 + s_row8;
                src = Ab + ((size_t)(m0 + row) * K + t * 64) * 2 + s_col16 * 16;
            } else {                                 // B chunk
                int row = (c - 32) * 8 + s_row8;
                src = Bb + ((size_t)(n0 + row) * K + t * 64) * 2 + s_col16 * 16;
            }
            __builtin_amdgcn_global_load_lds(
                (const __attribute__((address_space(1))) void*)src,
                (__attribute__((address_space(3))) void*)(smem + c * 1024), 16, 0, 0);
        }
        __syncthreads();   // drains vmcnt(0): tile resident

#pragma unroll
        for (int kk = 0; kk < 2; ++kk) {
            bf16x8 af[4], bf[4];
#pragma unroll
            for (int mi = 0; mi < 4; ++mi)
                af[mi] = *(const bf16x8*)(smem + (wm0 + mi * 16 + lr) * 128 + kk * 64 + lg * 16);
#pragma unroll
            for (int ni = 0; ni < 4; ++ni)
                bf[ni] = *(const bf16x8*)(smem + 32768 + (wn0 + ni * 16 + lr) * 128 + kk * 64 + lg * 16);
            __builtin_amdgcn_s_setprio(1);
#pragma unroll
            for (int mi = 0; mi < 4; ++mi)
#pragma unroll
                for (int ni = 0; ni < 4; ++ni)
                    acc[mi][ni] = __builtin_amdgcn_mfma_f32_16x16x32_bf16(
                        af[mi], bf[ni], acc[mi][ni], 0, 0, 0);
            __builtin_amdgcn_s_setprio(0);
        }
        __syncthreads();   // all reads done before next stage overwrites
    }

    // epilogue: D layout col = lane&15 (n), row = (lane>>4)*4 + r (m)
#pragma unroll
    for (int mi = 0; mi < 4; ++mi)
#pragma unroll
        for (int ni = 0; ni < 4; ++ni)
#pragma unroll
            for (int r = 0; r < 4; ++r) {
                int m = m0 + wm0 + mi * 16 + lg * 4 + r;
                int n = n0 + wn0 + ni * 16 + lr;
                float v = acc[mi][ni][r];
                int proj = n >> 10, nn = n & 1023;
                int h = nn >> 6, d = nn & 63;
                int bb = m >> 11, c = m & 2047;
                if (proj == 2) {
                    // Vt layout: [bh][d][2048]
                    Out[(size_t)2 * 8388608 +
                        ((size_t)((bb * 16 + h) * 64 + d)) * 2048 + c] = (__bf16)v;
                } else {
                    float scale = (proj == 0) ? 0.125f : 1.0f;
                    Out[(size_t)proj * 8388608 +
                        ((size_t)(bb * 16 + h) * 2048 + c) * 64 + d] = (__bf16)(v * scale);
                }
            }
}

// ---------------------------------------------------------------------------
// out-proj GEMM (m97 structure): 128x128 tile, BK=64, 256 threads (4 waves),
// single-buffer linear LDS 32KB, global_load_lds width=16.
// out[m][n] = sum_k A[m][k]*B[n][k]; f32 out row-major.
// ---------------------------------------------------------------------------
__launch_bounds__(256, 4)
__global__ void gemm_bt(const __bf16* __restrict__ A, const __bf16* __restrict__ Bm,
                        float* __restrict__ Out, int M, int N, int K) {
    __shared__ __align__(1024) char smem[32768];   // As [128][64] | Bs [128][64]
    const int tid = threadIdx.x;
    const int w = tid >> 6, lane = tid & 63;
    const int lr = lane & 15, lg = lane >> 4;
    const int wm0 = (w >> 1) * 64, wn0 = (w & 1) * 64;

    // bijective XCD swizzle (nwg % 8 == 0)
    const int nbx = gridDim.x;
    int id = blockIdx.y * nbx + blockIdx.x;
    int q8 = (nbx * gridDim.y) >> 3;
    int vid = (id & 7) * q8 + (id >> 3);
    const int m0 = (vid / nbx) * 128, n0 = (vid % nbx) * 128;

    const char* Ab = (const char*)A;
    const char* Bb = (const char*)Bm;

    f32x4 acc[4][4] = {};

    const int s_row8 = lane >> 3;
    const int s_col16 = lane & 7;

    const int nt = K >> 6;
    for (int t = 0; t < nt; ++t) {
#pragma unroll
        for (int r = 0; r < 4; ++r) {
            int c = w * 4 + r;
            int row = c * 8 + s_row8;
            const char* srcA = Ab + ((size_t)(m0 + row) * K + t * 64) * 2 + s_col16 * 16;
            const char* srcB = Bb + ((size_t)(n0 + row) * K + t * 64) * 2 + s_col16 * 16;
            __builtin_amdgcn_global_load_lds(
                (const __attribute__((address_space(1))) void*)srcA,
                (__attribute__((address_space(3))) void*)(smem + c * 1024), 16, 0, 0);
            __builtin_amdgcn_global_load_lds(
                (const __attribute__((address_space(1))) void*)srcB,
                (__attribute__((address_space(3))) void*)(smem + 16384 + c * 1024), 16, 0, 0);
        }
        __syncthreads();

#pragma unroll
        for (int kk = 0; kk < 2; ++kk) {
            bf16x8 af[4], bf[4];
#pragma unroll
            for (int mi = 0; mi < 4; ++mi)
                af[mi] = *(const bf16x8*)(smem + (wm0 + mi * 16 + lr) * 128 + kk * 64 + lg * 16);
#pragma unroll
            for (int ni = 0; ni < 4; ++ni)
                bf[ni] = *(const bf16x8*)(smem + 16384 + (wn0 + ni * 16 + lr) * 128 + kk * 64 + lg * 16);
            __builtin_amdgcn_s_setprio(1);
#pragma unroll
            for (int mi = 0; mi < 4; ++mi)
#pragma unroll
                for (int ni = 0; ni < 4; ++ni)
                    acc[mi][ni] = __builtin_amdgcn_mfma_f32_16x16x32_bf16(
                        af[mi], bf[ni], acc[mi][ni], 0, 0, 0);
            __builtin_amdgcn_s_setprio(0);
        }
        __syncthreads();
    }

#pragma unroll
    for (int mi = 0; mi < 4; ++mi)
#pragma unroll
        for (int ni = 0; ni < 4; ++ni)
#pragma unroll
            for (int r = 0; r < 4; ++r) {
                int m = m0 + wm0 + mi * 16 + lg * 4 + r;
                int n = n0 + wn0 + ni * 16 + lr;
                Out[(size_t)m * N + n] = acc[mi][ni][r];
            }
}

// ---------------------------------------------------------------------------
// Flash attention (causal), swapped-QK^T structure.
// Grid: 1024 blocks (XCD-swizzled). Block = (bh, q-tile pair {qt, 31-qt}).
// 4 waves x 16 q-rows each. K tile + V^T tile double-buffered in LDS via
// global_load_lds with XOR-swizzled source (linear dest) + swizzled reads.
// ---------------------------------------------------------------------------
__device__ __forceinline__ unsigned swz(unsigned d) {
    return d ^ (((d >> 7) & 7) << 4);   // 128B rows; spread 16B slots across banks
}

__launch_bounds__(256, 4)
__global__ void attn_fwd(const __bf16* __restrict__ Q, const __bf16* __restrict__ K,
                         const __bf16* __restrict__ Vt, __bf16* __restrict__ Aout) {
    // LDS: K dbuf 2x8KB | Vt dbuf 2x8KB | P 4 waves x 2KB  = 40960 B
    __shared__ char smem[40960];
    const int id = blockIdx.x;
    const int vid = (id & 7) * 128 + (id >> 3);   // bijective XCD swizzle (1024%8==0)
    const int bh = vid >> 4, pr = vid & 15;
    const int w = threadIdx.x >> 6, lane = threadIdx.x & 63;
    const int lr = lane & 15, lg = lane >> 4;
    const char* Kb  = (const char*)(K  + (size_t)bh * 2048 * 64);
    const char* Vtb = (const char*)(Vt + (size_t)bh * 64 * 2048);
    const __bf16* Qb = Q + (size_t)bh * 2048 * 64;
    const int b = bh >> 4, h = bh & 15;
    char* Pb = smem + 32768 + w * 2048;

    for (int pass = 0; pass < 2; ++pass) {
        const int qt = pass ? pr : 31 - pr;       // pair work = 33 tiles, uniform
        const int q0 = qt * 64 + w * 16;
        const int nt = qt + 1;

        bf16x8 qf[2];
#pragma unroll
        for (int kk = 0; kk < 2; ++kk)
            qf[kk] = *(const bf16x8*)&Qb[(size_t)(q0 + lr) * 64 + kk * 32 + lg * 8];

        f32x4 o[4] = {};
        float m = NEG_INF, l = 0.f;

        __syncthreads();   // previous pass/compute fully done before restaging buf0
        // prologue: stage tile 0 -> buf 0 (4x global_load_lds per wave)
        {
            char* kd = smem;
            char* vd = smem + 16384;
#pragma unroll
            for (int i = 0; i < 2; ++i) {
                unsigned c = (unsigned)(w * 2 + i);
                unsigned d = c * 1024 + (unsigned)lane * 16;
                unsigned bs = swz(d);
                __builtin_amdgcn_global_load_lds(
                    (const __attribute__((address_space(1))) void*)(Kb + bs),
                    (__attribute__((address_space(3))) void*)(kd + c * 1024), 16, 0, 0);
                unsigned row = bs >> 7, colb = bs & 127;
                __builtin_amdgcn_global_load_lds(
                    (const __attribute__((address_space(1))) void*)(Vtb + (size_t)row * 4096 + colb),
                    (__attribute__((address_space(3))) void*)(vd + c * 1024), 16, 0, 0);
            }
        }

        for (int t = 0; t < nt; ++t) {
            __syncthreads();   // implicit vmcnt(0) drain: tile t resident; all waves synced
            if (t + 1 < nt) {  // prefetch t+1 while computing t
                char* kd = smem + ((t + 1) & 1) * 8192;
                char* vd = smem + 16384 + ((t + 1) & 1) * 8192;
#pragma unroll
                for (int i = 0; i < 2; ++i) {
                    unsigned c = (unsigned)(w * 2 + i);
                    unsigned d = c * 1024 + (unsigned)lane * 16;
                    unsigned bs = swz(d);
                    __builtin_amdgcn_global_load_lds(
                        (const __attribute__((address_space(1))) void*)(Kb + (size_t)(t + 1) * 8192 + bs),
                        (__attribute__((address_space(3))) void*)(kd + c * 1024), 16, 0, 0);
                    unsigned row = bs >> 7, colb = bs & 127;
                    __builtin_amdgcn_global_load_lds(
                        (const __attribute__((address_space(1))) void*)(Vtb + (size_t)row * 4096 +
                                                                       (size_t)(t + 1) * 128 + colb),
                        (__attribute__((address_space(3))) void*)(vd + c * 1024), 16, 0, 0);
                }
            }
            const char* Ks = smem + (t & 1) * 8192;
            const char* Vs = smem + 16384 + (t & 1) * 8192;
            const int k0 = t * 64;

            // S^T = K·Q^T : lane owns full row q = q0+lr; s[sub][r] = S[q][k0+sub*16+lg*4+r]
            f32x4 s[4] = {};
#pragma unroll
            for (int kk = 0; kk < 2; ++kk)
#pragma unroll
                for (int sub = 0; sub < 4; ++sub) {
                    bf16x8 kf = *(const bf16x8*)(Ks + swz((unsigned)((sub * 16 + lr) * 128 + kk * 64 + lg * 16)));
                    s[sub] = __builtin_amdgcn_mfma_f32_16x16x32_bf16(kf, qf[kk], s[sub], 0, 0, 0);
                }
            if (t == qt) {
#pragma unroll
                for (int sub = 0; sub < 4; ++sub)
#pragma unroll
                    for (int r = 0; r < 4; ++r)
                        if (k0 + sub * 16 + lg * 4 + r > q0 + lr) s[sub][r] = NEG_INF;
            }
            // online softmax: 16 local vals + 2 shuffles across lg groups
            float mloc = NEG_INF;
#pragma unroll
            for (int sub = 0; sub < 4; ++sub)
#pragma unroll
                for (int r = 0; r < 4; ++r) mloc = fmaxf(mloc, s[sub][r]);
            mloc = fmaxf(mloc, __shfl_xor(mloc, 16));
            mloc = fmaxf(mloc, __shfl_xor(mloc, 32));
            float mnew = fmaxf(m, mloc);
            float alpha = __expf(m - mnew);
            float rs = 0.f;
#pragma unroll
            for (int sub = 0; sub < 4; ++sub)
#pragma unroll
                for (int r = 0; r < 4; ++r) {
                    float p = __expf(s[sub][r] - mnew);
                    s[sub][r] = p;
                    rs += p;
                }
            rs += __shfl_xor(rs, 16);
            rs += __shfl_xor(rs, 32);
            l = l * alpha + rs;
            m = mnew;
#pragma unroll
            for (int ni = 0; ni < 4; ++ni) o[ni] *= alpha;

            // P -> per-wave LDS (vectorized b64 writes, swizzled)
#pragma unroll
            for (int sub = 0; sub < 4; ++sub) {
                bf16x4 pk;
#pragma unroll
                for (int r = 0; r < 4; ++r) pk[r] = (__bf16)s[sub][r];
                *(bf16x4*)(Pb + swz((unsigned)(lr * 128 + sub * 32 + lg * 8))) = pk;
            }
            bf16x8 pfr[2];
#pragma unroll
            for (int kk = 0; kk < 2; ++kk)
                pfr[kk] = *(const bf16x8*)(Pb + swz((unsigned)(lr * 128 + kk * 64 + lg * 16)));

            // O^T += V^T · P^T : o[ni][r] = O[q=q0+lr][d = ni*16 + lg*4 + r]
#pragma unroll
            for (int kk = 0; kk < 2; ++kk)
#pragma unroll
                for (int ni = 0; ni < 4; ++ni) {
                    bf16x8 vf = *(const bf16x8*)(Vs + swz((unsigned)((ni * 16 + lr) * 128 + kk * 64 + lg * 16)));
                    o[ni] = __builtin_amdgcn_mfma_f32_16x16x32_bf16(vf, pfr[kk], o[ni], 0, 0, 0);
                }
        }

        // epilogue: Aout[b][c=q0+lr][h*64 + ni*16 + lg*4 + r], vectorized 8B stores
        float rinv = 1.0f / l;
#pragma unroll
        for (int ni = 0; ni < 4; ++ni) {
            bf16x4 ov;
#pragma unroll
            for (int r = 0; r < 4; ++r) ov[r] = (__bf16)(o[ni][r] * rinv);
            *(bf16x4*)&Aout[((size_t)b * 2048 + q0 + lr) * 1024 + h * 64 + ni * 16 + lg * 4] = ov;
        }
    }
}

// ---------------------------------------------------------------------------
// launch
// ---------------------------------------------------------------------------
extern "C" void kernel_launch(void* const* d_in, const int* in_sizes, int n_in,
                              void* d_out, int out_size, void* d_ws, size_t ws_size,
                              hipStream_t stream) {
    const float* x  = (const float*)d_in[0];
    const float* Wk = (const float*)d_in[1];   // dict order: x, Wk, Wq, Wv, Wo
    const float* Wq = (const float*)d_in[2];
    const float* Wv = (const float*)d_in[3];
    const float* Wo = (const float*)d_in[4];

    char* ws = (char*)d_ws;
    __bf16* xb   = (__bf16*)(ws);                 // [8192][1024]        16 MB
    __bf16* wqkv = (__bf16*)(ws + 16777216);      // [3072][1024]         6 MB
    __bf16* wo_b = (__bf16*)(ws + 23068672);      // [1024][1024]         2 MB
    __bf16* qkv  = (__bf16*)(ws + 25165824);      // Q,K: [64][2048][64]; Vt: [64][64][2048]
    __bf16* aout = (__bf16*)(ws + 75497472);      // [8192][1024]        16 MB
    float* out = (float*)d_out;

    cvt_f32_bf16<<<2048, 256, 0, stream>>>(x, xb, 8388608);
    cvt_f32_bf16<<<1024, 256, 0, stream>>>(Wq, wqkv, 1048576);            // proj 0 = Q
    cvt_f32_bf16<<<1024, 256, 0, stream>>>(Wk, wqkv + 1048576, 1048576);  // proj 1 = K
    cvt_f32_bf16<<<1024, 256, 0, stream>>>(Wv, wqkv + 2097152, 1048576);  // proj 2 = V
    cvt_f32_bf16<<<1024, 256, 0, stream>>>(Wo, wo_b, 1048576);

    gemm_qkv<<<dim3(768), 512, 0, stream>>>(xb, wqkv, qkv, 8192, 3072, 1024);
    attn_fwd<<<dim3(1024), 256, 0, stream>>>(qkv, qkv + 8388608, qkv + 16777216, aout);
    gemm_bt<<<dim3(8, 64), 256, 0, stream>>>(aout, wo_b, out, 8192, 1024, 1024);
}

// Round 7
// 224.823 us; speedup vs baseline: 2.7853x; 2.7853x over previous
//
#include <hip/hip_runtime.h>
#include <hip/hip_bf16.h>

typedef __bf16 bf16x8 __attribute__((ext_vector_type(8)));
typedef __bf16 bf16x4 __attribute__((ext_vector_type(4)));
typedef float f32x4 __attribute__((ext_vector_type(4)));

#define NEG_INF (-__builtin_inff())
#define BAR() do { asm volatile("" ::: "memory"); __builtin_amdgcn_s_barrier(); asm volatile("" ::: "memory"); } while (0)
#define VMCNT8() asm volatile("s_waitcnt vmcnt(8)" ::: "memory")
#define VMCNT0() asm volatile("s_waitcnt vmcnt(0)" ::: "memory")

// ---------------------------------------------------------------------------
// f32 -> bf16 conversion (vectorized, grid-stride)
// ---------------------------------------------------------------------------
__global__ void cvt_f32_bf16(const float* __restrict__ src, __bf16* __restrict__ dst, int n) {
    int idx = blockIdx.x * blockDim.x + threadIdx.x;
    int stride = gridDim.x * blockDim.x;
    for (int i = idx * 4; i < n; i += stride * 4) {
        float4 v = *(const float4*)(src + i);
        bf16x4 o;
        o[0] = (__bf16)v.x; o[1] = (__bf16)v.y; o[2] = (__bf16)v.z; o[3] = (__bf16)v.w;
        *(bf16x4*)(dst + i) = o;
    }
}

// ---------------------------------------------------------------------------
// QKV GEMM, 8-phase 256x256 (race-fixed counted-vmcnt schedule).
// M=8192 N=3072 K=1024. 512 threads = 8 waves (2M x 4N), acc[8][4].
// LDS 128KB = 2 buf x 4 regions x 16KB (r0=A rows0-127, r1=A rows128-255,
// r2=B rows0-127, r3=B rows128-255). global_load_lds w16, linear dest +
// involution-swizzled source; ds_read same XOR.
// Staging: region staged IMMEDIATELY after its reads complete (B at ph3/ph7,
// A at ph4/ph8); waits vmcnt(8) at ph4/ph8 retire a whole tile staged 4-5
// phases earlier. Outstanding-count verified: 16 -> wait -> 8 steady cycle.
// ---------------------------------------------------------------------------
__launch_bounds__(512, 2)
__global__ void gemm8_qkv(const __bf16* __restrict__ A, const __bf16* __restrict__ Bm,
                          __bf16* __restrict__ Out) {
    __shared__ __align__(1024) char smem[131072];
    const int K = 1024;
    const int tid = threadIdx.x;
    const int w = tid >> 6, lane = tid & 63;
    const int lr = lane & 15, lg = lane >> 4;
    const int wr = w >> 2, wc = w & 3;

    // bijective XCD swizzle: 384 blocks (32 m-rows x 12 n-cols), 384%8==0
    int id = blockIdx.x;
    int vid = (id & 7) * 48 + (id >> 3);
    const int m0 = (vid / 12) * 256, n0 = (vid % 12) * 256;

    const char* Ab = (const char*)A;
    const char* Bb = (const char*)Bm;

    f32x4 acc[8][4] = {};
    bf16x8 af[4][2], bf0[2][2], bf1[2][2];

    // stage region r (16KB) of K-tile t into buf t&1. 2 loads/lane.
    auto stage = [&](int t, int r) {
        char* rbase = smem + (t & 1) * 65536 + r * 16384;
#pragma unroll
        for (int i = 0; i < 2; ++i) {
            unsigned c = (unsigned)(w * 2 + i);                // chunk 0..15, wave-uniform
            unsigned drel = c * 1024 + (unsigned)lane * 16;
            unsigned s = drel ^ (((drel >> 7) & 7) << 4);      // involution
            unsigned srow = s >> 7, scol = s & 127;
            const char* src = (r < 2)
                ? Ab + ((size_t)(m0 + (r & 1) * 128 + srow) * K + t * 64) * 2 + scol
                : Bb + ((size_t)(n0 + (r & 1) * 128 + srow) * K + t * 64) * 2 + scol;
            __builtin_amdgcn_global_load_lds(
                (const __attribute__((address_space(1))) void*)src,
                (__attribute__((address_space(3))) void*)(rbase + drel), 16, 0, 0);
        }
    };
    auto rdA = [&](int mh, const char* bufb) {                 // region wr, rows mh*64..+63
        const char* rb = bufb + wr * 16384;
#pragma unroll
        for (int mi = 0; mi < 4; ++mi)
#pragma unroll
            for (int kk = 0; kk < 2; ++kk) {
                unsigned d = (unsigned)((mh * 64 + mi * 16 + lr) * 128 + kk * 64 + lg * 16);
                af[mi][kk] = *(const bf16x8*)(rb + (d ^ (((d >> 7) & 7) << 4)));
            }
    };
    auto rdB = [&](bf16x8 (&bf)[2][2], int nh, const char* bufb) {  // region 2+(wc>>1)
        const char* rb = bufb + (2 + (wc >> 1)) * 16384;
#pragma unroll
        for (int ni = 0; ni < 2; ++ni)
#pragma unroll
            for (int kk = 0; kk < 2; ++kk) {
                unsigned d = (unsigned)(((wc & 1) * 64 + nh * 32 + ni * 16 + lr) * 128 + kk * 64 + lg * 16);
                bf[ni][kk] = *(const bf16x8*)(rb + (d ^ (((d >> 7) & 7) << 4)));
            }
    };
    auto mma = [&](bf16x8 (&bf)[2][2], int mh, int nh) {       // 16 MFMA, one C-quadrant
        __builtin_amdgcn_s_setprio(1);
#pragma unroll
        for (int mi = 0; mi < 4; ++mi)
#pragma unroll
            for (int ni = 0; ni < 2; ++ni)
#pragma unroll
                for (int kk = 0; kk < 2; ++kk)
                    acc[mh * 4 + mi][nh * 2 + ni] = __builtin_amdgcn_mfma_f32_16x16x32_bf16(
                        af[mi][kk], bf[ni][kk], acc[mh * 4 + mi][nh * 2 + ni], 0, 0, 0);
        __builtin_amdgcn_s_setprio(0);
    };

    // prologue: T0 (all 4 regions -> buf0), T1 (all 4 -> buf1) = 16 loads/lane
    stage(0, 2); stage(0, 3); stage(0, 0); stage(0, 1);
    stage(1, 2); stage(1, 3); stage(1, 0); stage(1, 1);
    VMCNT8();            // retires oldest 8 = all of T0; T1's 8 in flight
    BAR();

    const char* b0 = smem;
    const char* b1 = smem + 65536;
    for (int i = 0; i < 8; ++i) {
        const int T = 2 * i;
        const bool more = (i < 7);
        // ---- tile T from buf0 ----
        // phase 1
        rdA(0, b0); rdB(bf0, 0, b0);
        BAR(); mma(bf0, 0, 0); BAR();
        // phase 2 (B regions of buf0 fully read after this phase)
        rdB(bf1, 1, b0);
        BAR(); mma(bf1, 0, 1); BAR();
        // phase 3: B reads of buf0 done -> stage T+2 B regions into buf0
        rdA(1, b0);
        if (more) { stage(T + 2, 2); stage(T + 2, 3); }
        BAR(); mma(bf0, 1, 0); BAR();
        // phase 4: A reads of buf0 done -> stage T+2 A; wait T+1 resident
        if (more) { stage(T + 2, 0); stage(T + 2, 1); VMCNT8(); }
        else      { VMCNT0(); }
        BAR(); mma(bf1, 1, 1); BAR();
        // ---- tile T+1 from buf1 ----
        // phase 5
        rdA(0, b1); rdB(bf0, 0, b1);
        BAR(); mma(bf0, 0, 0); BAR();
        // phase 6
        rdB(bf1, 1, b1);
        BAR(); mma(bf1, 0, 1); BAR();
        // phase 7: stage T+3 B regions into buf1
        rdA(1, b1);
        if (more) { stage(T + 3, 2); stage(T + 3, 3); }
        BAR(); mma(bf0, 1, 0); BAR();
        // phase 8: stage T+3 A; wait T+2 resident (next iter reads buf0)
        if (more) { stage(T + 3, 0); stage(T + 3, 1); VMCNT8(); }
        BAR(); mma(bf1, 1, 1); BAR();
    }

    // epilogue: D layout col = lane&15 (n), row = (lane>>4)*4 + r (m)
#pragma unroll
    for (int mh = 0; mh < 2; ++mh)
#pragma unroll
        for (int mi = 0; mi < 4; ++mi)
#pragma unroll
            for (int nh = 0; nh < 2; ++nh)
#pragma unroll
                for (int ni = 0; ni < 2; ++ni)
#pragma unroll
                    for (int r = 0; r < 4; ++r) {
                        int m = m0 + wr * 128 + mh * 64 + mi * 16 + lg * 4 + r;
                        int n = n0 + wc * 64 + nh * 32 + ni * 16 + lr;
                        float v = acc[mh * 4 + mi][nh * 2 + ni][r];
                        int proj = n >> 10, nn = n & 1023;
                        int h = nn >> 6, d = nn & 63;
                        int bb = m >> 11, c = m & 2047;
                        if (proj == 2) {
                            Out[(size_t)2 * 8388608 +
                                ((size_t)((bb * 16 + h) * 64 + d)) * 2048 + c] = (__bf16)v;
                        } else {
                            float scale = (proj == 0) ? 0.125f : 1.0f;
                            Out[(size_t)proj * 8388608 +
                                ((size_t)(bb * 16 + h) * 2048 + c) * 64 + d] = (__bf16)(v * scale);
                        }
                    }
}

// ---------------------------------------------------------------------------
// out-proj GEMM (m97 structure, r4-proven): 128x128 tile, BK=64, 4 waves,
// single-buffer linear LDS 32KB, global_load_lds width=16, 2 barriers/step.
// ---------------------------------------------------------------------------
__launch_bounds__(256, 4)
__global__ void gemm_bt(const __bf16* __restrict__ A, const __bf16* __restrict__ Bm,
                        float* __restrict__ Out, int M, int N, int K) {
    __shared__ __align__(1024) char smem[32768];
    const int tid = threadIdx.x;
    const int w = tid >> 6, lane = tid & 63;
    const int lr = lane & 15, lg = lane >> 4;
    const int wm0 = (w >> 1) * 64, wn0 = (w & 1) * 64;

    const int nbx = gridDim.x;
    int id = blockIdx.y * nbx + blockIdx.x;
    int q8 = (nbx * gridDim.y) >> 3;
    int vid = (id & 7) * q8 + (id >> 3);
    const int m0 = (vid / nbx) * 128, n0 = (vid % nbx) * 128;

    const char* Ab = (const char*)A;
    const char* Bb = (const char*)Bm;

    f32x4 acc[4][4] = {};
    const int s_row8 = lane >> 3;
    const int s_col16 = lane & 7;

    const int nt = K >> 6;
    for (int t = 0; t < nt; ++t) {
#pragma unroll
        for (int r = 0; r < 4; ++r) {
            int c = w * 4 + r;
            int row = c * 8 + s_row8;
            const char* srcA = Ab + ((size_t)(m0 + row) * K + t * 64) * 2 + s_col16 * 16;
            const char* srcB = Bb + ((size_t)(n0 + row) * K + t * 64) * 2 + s_col16 * 16;
            __builtin_amdgcn_global_load_lds(
                (const __attribute__((address_space(1))) void*)srcA,
                (__attribute__((address_space(3))) void*)(smem + c * 1024), 16, 0, 0);
            __builtin_amdgcn_global_load_lds(
                (const __attribute__((address_space(1))) void*)srcB,
                (__attribute__((address_space(3))) void*)(smem + 16384 + c * 1024), 16, 0, 0);
        }
        __syncthreads();
#pragma unroll
        for (int kk = 0; kk < 2; ++kk) {
            bf16x8 af[4], bf[4];
#pragma unroll
            for (int mi = 0; mi < 4; ++mi)
                af[mi] = *(const bf16x8*)(smem + (wm0 + mi * 16 + lr) * 128 + kk * 64 + lg * 16);
#pragma unroll
            for (int ni = 0; ni < 4; ++ni)
                bf[ni] = *(const bf16x8*)(smem + 16384 + (wn0 + ni * 16 + lr) * 128 + kk * 64 + lg * 16);
            __builtin_amdgcn_s_setprio(1);
#pragma unroll
            for (int mi = 0; mi < 4; ++mi)
#pragma unroll
                for (int ni = 0; ni < 4; ++ni)
                    acc[mi][ni] = __builtin_amdgcn_mfma_f32_16x16x32_bf16(
                        af[mi], bf[ni], acc[mi][ni], 0, 0, 0);
            __builtin_amdgcn_s_setprio(0);
        }
        __syncthreads();
    }
#pragma unroll
    for (int mi = 0; mi < 4; ++mi)
#pragma unroll
        for (int ni = 0; ni < 4; ++ni)
#pragma unroll
            for (int r = 0; r < 4; ++r) {
                int m = m0 + wm0 + mi * 16 + lg * 4 + r;
                int n = n0 + wn0 + ni * 16 + lr;
                Out[(size_t)m * N + n] = acc[mi][ni][r];
            }
}

// ---------------------------------------------------------------------------
// Flash attention (causal), swapped-QK^T structure (r2-proven, unchanged).
// ---------------------------------------------------------------------------
__device__ __forceinline__ unsigned swz(unsigned d) {
    return d ^ (((d >> 7) & 7) << 4);
}

__launch_bounds__(256, 4)
__global__ void attn_fwd(const __bf16* __restrict__ Q, const __bf16* __restrict__ K,
                         const __bf16* __restrict__ Vt, __bf16* __restrict__ Aout) {
    __shared__ char smem[40960];
    const int id = blockIdx.x;
    const int vid = (id & 7) * 128 + (id >> 3);
    const int bh = vid >> 4, pr = vid & 15;
    const int w = threadIdx.x >> 6, lane = threadIdx.x & 63;
    const int lr = lane & 15, lg = lane >> 4;
    const char* Kb  = (const char*)(K  + (size_t)bh * 2048 * 64);
    const char* Vtb = (const char*)(Vt + (size_t)bh * 64 * 2048);
    const __bf16* Qb = Q + (size_t)bh * 2048 * 64;
    const int b = bh >> 4, h = bh & 15;
    char* Pb = smem + 32768 + w * 2048;

    for (int pass = 0; pass < 2; ++pass) {
        const int qt = pass ? pr : 31 - pr;
        const int q0 = qt * 64 + w * 16;
        const int nt = qt + 1;

        bf16x8 qf[2];
#pragma unroll
        for (int kk = 0; kk < 2; ++kk)
            qf[kk] = *(const bf16x8*)&Qb[(size_t)(q0 + lr) * 64 + kk * 32 + lg * 8];

        f32x4 o[4] = {};
        float m = NEG_INF, l = 0.f;

        __syncthreads();
        {
            char* kd = smem;
            char* vd = smem + 16384;
#pragma unroll
            for (int i = 0; i < 2; ++i) {
                unsigned c = (unsigned)(w * 2 + i);
                unsigned d = c * 1024 + (unsigned)lane * 16;
                unsigned bs = swz(d);
                __builtin_amdgcn_global_load_lds(
                    (const __attribute__((address_space(1))) void*)(Kb + bs),
                    (__attribute__((address_space(3))) void*)(kd + c * 1024), 16, 0, 0);
                unsigned row = bs >> 7, colb = bs & 127;
                __builtin_amdgcn_global_load_lds(
                    (const __attribute__((address_space(1))) void*)(Vtb + (size_t)row * 4096 + colb),
                    (__attribute__((address_space(3))) void*)(vd + c * 1024), 16, 0, 0);
            }
        }

        for (int t = 0; t < nt; ++t) {
            __syncthreads();
            if (t + 1 < nt) {
                char* kd = smem + ((t + 1) & 1) * 8192;
                char* vd = smem + 16384 + ((t + 1) & 1) * 8192;
#pragma unroll
                for (int i = 0; i < 2; ++i) {
                    unsigned c = (unsigned)(w * 2 + i);
                    unsigned d = c * 1024 + (unsigned)lane * 16;
                    unsigned bs = swz(d);
                    __builtin_amdgcn_global_load_lds(
                        (const __attribute__((address_space(1))) void*)(Kb + (size_t)(t + 1) * 8192 + bs),
                        (__attribute__((address_space(3))) void*)(kd + c * 1024), 16, 0, 0);
                    unsigned row = bs >> 7, colb = bs & 127;
                    __builtin_amdgcn_global_load_lds(
                        (const __attribute__((address_space(1))) void*)(Vtb + (size_t)row * 4096 +
                                                                       (size_t)(t + 1) * 128 + colb),
                        (__attribute__((address_space(3))) void*)(vd + c * 1024), 16, 0, 0);
                }
            }
            const char* Ks = smem + (t & 1) * 8192;
            const char* Vs = smem + 16384 + (t & 1) * 8192;
            const int k0 = t * 64;

            f32x4 s[4] = {};
#pragma unroll
            for (int kk = 0; kk < 2; ++kk)
#pragma unroll
                for (int sub = 0; sub < 4; ++sub) {
                    bf16x8 kf = *(const bf16x8*)(Ks + swz((unsigned)((sub * 16 + lr) * 128 + kk * 64 + lg * 16)));
                    s[sub] = __builtin_amdgcn_mfma_f32_16x16x32_bf16(kf, qf[kk], s[sub], 0, 0, 0);
                }
            if (t == qt) {
#pragma unroll
                for (int sub = 0; sub < 4; ++sub)
#pragma unroll
                    for (int r = 0; r < 4; ++r)
                        if (k0 + sub * 16 + lg * 4 + r > q0 + lr) s[sub][r] = NEG_INF;
            }
            float mloc = NEG_INF;
#pragma unroll
            for (int sub = 0; sub < 4; ++sub)
#pragma unroll
                for (int r = 0; r < 4; ++r) mloc = fmaxf(mloc, s[sub][r]);
            mloc = fmaxf(mloc, __shfl_xor(mloc, 16));
            mloc = fmaxf(mloc, __shfl_xor(mloc, 32));
            float mnew = fmaxf(m, mloc);
            float alpha = __expf(m - mnew);
            float rs = 0.f;
#pragma unroll
            for (int sub = 0; sub < 4; ++sub)
#pragma unroll
                for (int r = 0; r < 4; ++r) {
                    float p = __expf(s[sub][r] - mnew);
                    s[sub][r] = p;
                    rs += p;
                }
            rs += __shfl_xor(rs, 16);
            rs += __shfl_xor(rs, 32);
            l = l * alpha + rs;
            m = mnew;
#pragma unroll
            for (int ni = 0; ni < 4; ++ni) o[ni] *= alpha;

#pragma unroll
            for (int sub = 0; sub < 4; ++sub) {
                bf16x4 pk;
#pragma unroll
                for (int r = 0; r < 4; ++r) pk[r] = (__bf16)s[sub][r];
                *(bf16x4*)(Pb + swz((unsigned)(lr * 128 + sub * 32 + lg * 8))) = pk;
            }
            bf16x8 pfr[2];
#pragma unroll
            for (int kk = 0; kk < 2; ++kk)
                pfr[kk] = *(const bf16x8*)(Pb + swz((unsigned)(lr * 128 + kk * 64 + lg * 16)));

#pragma unroll
            for (int kk = 0; kk < 2; ++kk)
#pragma unroll
                for (int ni = 0; ni < 4; ++ni) {
                    bf16x8 vf = *(const bf16x8*)(Vs + swz((unsigned)((ni * 16 + lr) * 128 + kk * 64 + lg * 16)));
                    o[ni] = __builtin_amdgcn_mfma_f32_16x16x32_bf16(vf, pfr[kk], o[ni], 0, 0, 0);
                }
        }

        float rinv = 1.0f / l;
#pragma unroll
        for (int ni = 0; ni < 4; ++ni) {
            bf16x4 ov;
#pragma unroll
            for (int r = 0; r < 4; ++r) ov[r] = (__bf16)(o[ni][r] * rinv);
            *(bf16x4*)&Aout[((size_t)b * 2048 + q0 + lr) * 1024 + h * 64 + ni * 16 + lg * 4] = ov;
        }
    }
}

// ---------------------------------------------------------------------------
// launch
// ---------------------------------------------------------------------------
extern "C" void kernel_launch(void* const* d_in, const int* in_sizes, int n_in,
                              void* d_out, int out_size, void* d_ws, size_t ws_size,
                              hipStream_t stream) {
    const float* x  = (const float*)d_in[0];
    const float* Wk = (const float*)d_in[1];   // dict order: x, Wk, Wq, Wv, Wo
    const float* Wq = (const float*)d_in[2];
    const float* Wv = (const float*)d_in[3];
    const float* Wo = (const float*)d_in[4];

    char* ws = (char*)d_ws;
    __bf16* xb   = (__bf16*)(ws);                 // [8192][1024]        16 MB
    __bf16* wqkv = (__bf16*)(ws + 16777216);      // [3072][1024]         6 MB
    __bf16* wo_b = (__bf16*)(ws + 23068672);      // [1024][1024]         2 MB
    __bf16* qkv  = (__bf16*)(ws + 25165824);      // Q,K: [64][2048][64]; Vt: [64][64][2048]
    __bf16* aout = (__bf16*)(ws + 75497472);      // [8192][1024]        16 MB
    float* out = (float*)d_out;

    cvt_f32_bf16<<<2048, 256, 0, stream>>>(x, xb, 8388608);
    cvt_f32_bf16<<<1024, 256, 0, stream>>>(Wq, wqkv, 1048576);            // proj 0 = Q
    cvt_f32_bf16<<<1024, 256, 0, stream>>>(Wk, wqkv + 1048576, 1048576);  // proj 1 = K
    cvt_f32_bf16<<<1024, 256, 0, stream>>>(Wv, wqkv + 2097152, 1048576);  // proj 2 = V
    cvt_f32_bf16<<<1024, 256, 0, stream>>>(Wo, wo_b, 1048576);

    gemm8_qkv<<<dim3(384), 512, 0, stream>>>(xb, wqkv, qkv);
    attn_fwd<<<dim3(1024), 256, 0, stream>>>(qkv, qkv + 8388608, qkv + 16777216, aout);
    gemm_bt<<<dim3(8, 64), 256, 0, stream>>>(aout, wo_b, out, 8192, 1024, 1024);
}

// Round 8
// 218.299 us; speedup vs baseline: 2.8685x; 1.0299x over previous
//
#include <hip/hip_runtime.h>
#include <hip/hip_bf16.h>

typedef __bf16 bf16x8 __attribute__((ext_vector_type(8)));
typedef __bf16 bf16x4 __attribute__((ext_vector_type(4)));
typedef float f32x4 __attribute__((ext_vector_type(4)));

#define NEG_INF (-__builtin_inff())

// ---------------------------------------------------------------------------
// f32 -> bf16 conversion for x (vectorized, grid-stride)
// ---------------------------------------------------------------------------
__global__ void cvt_f32_bf16(const float* __restrict__ src, __bf16* __restrict__ dst, int n) {
    int idx = blockIdx.x * blockDim.x + threadIdx.x;
    int stride = gridDim.x * blockDim.x;
    for (int i = idx * 4; i < n; i += stride * 4) {
        float4 v = *(const float4*)(src + i);
        bf16x4 o;
        o[0] = (__bf16)v.x; o[1] = (__bf16)v.y; o[2] = (__bf16)v.z; o[3] = (__bf16)v.w;
        *(bf16x4*)(dst + i) = o;
    }
}

// ---------------------------------------------------------------------------
// All four weight matrices (1M elements each) in ONE launch.
// Wq,Wk,Wv -> wqkv (contiguous, proj order Q,K,V); Wo -> wo_b.
// Grid 4096 x 256, 4 elements/thread, no loop.
// ---------------------------------------------------------------------------
__global__ void cvt_weights(const float* __restrict__ Wq, const float* __restrict__ Wk,
                            const float* __restrict__ Wv, const float* __restrict__ Wo,
                            __bf16* __restrict__ wqkv, __bf16* __restrict__ wo_b) {
    int i = (blockIdx.x * blockDim.x + threadIdx.x) * 4;
    int sel = i >> 20;            // 0..3
    int off = i & 1048575;
    const float* src = (sel == 0) ? Wq : (sel == 1) ? Wk : (sel == 2) ? Wv : Wo;
    __bf16* dst = (sel < 3) ? (wqkv + (size_t)sel * 1048576) : wo_b;
    float4 v = *(const float4*)(src + off);
    bf16x4 o;
    o[0] = (__bf16)v.x; o[1] = (__bf16)v.y; o[2] = (__bf16)v.z; o[3] = (__bf16)v.w;
    *(bf16x4*)(dst + off) = o;
}

// ---------------------------------------------------------------------------
// GEMM: 256x128 tile, BK=64, 512 threads (8 waves as 4m x 2n), m97 schedule:
// single-buffer linear LDS (A 256x64 = 32KB | B 128x64 = 16KB), staged by
// global_load_lds width=16, 2 barriers per K-step.
// out[m][n] = sum_k A[m][k]*B[n][k]  (A:[M][K], B:[N][K], bf16).
// MODE 0: bf16 out scattered to QKV layout; Q scaled 1/8; V transposed
//         to Vt[bh][d][2048].  (N=3072, grid 768 = 3 CU-rounds)
// MODE 1: f32 out row-major [M][N].  (N=1024, grid 256 = 1 CU-round)
// NOTE: __launch_bounds__(512,2) -> VGPR cap 256 (r5's (512,6) spill bug fixed).
// ---------------------------------------------------------------------------
template <int MODE>
__launch_bounds__(512, 2)
__global__ void gemm256(const __bf16* __restrict__ A, const __bf16* __restrict__ Bm,
                        void* __restrict__ Out, int M, int N, int K) {
    __shared__ __align__(1024) char smem[49152];   // A [256][64] | B [128][64]
    const int tid = threadIdx.x;
    const int w = tid >> 6, lane = tid & 63;
    const int lr = lane & 15, lg = lane >> 4;
    const int wm0 = (w >> 1) * 64, wn0 = (w & 1) * 64;

    // bijective XCD swizzle (nwg % 8 == 0 for both call sites)
    const int nbx = N >> 7;                   // 24 or 8
    int id = blockIdx.x;
    int q8 = (int)(gridDim.x) >> 3;
    int vid = (id & 7) * q8 + (id >> 3);
    const int m0 = (vid / nbx) * 256, n0 = (vid % nbx) * 128;

    const char* Ab = (const char*)A;
    const char* Bb = (const char*)Bm;

    f32x4 acc[4][4] = {};

    const int s_row8 = lane >> 3;   // 0..7
    const int s_col16 = lane & 7;   // 0..7

    const int nt = K >> 6;          // 16
    for (int t = 0; t < nt; ++t) {
        // stage 48KB: 48 chunks of 1KB; wave w covers chunks 6w..6w+5
#pragma unroll
        for (int i = 0; i < 6; ++i) {
            int c = w * 6 + i;                       // wave-uniform 0..47
            const char* src;
            if (c < 32) {                            // A chunk: rows c*8..c*8+7
                int row = c * 8 + s_row8;
                src = Ab + ((size_t)(m0 + row) * K + t * 64) * 2 + s_col16 * 16;
            } else {                                 // B chunk
                int row = (c - 32) * 8 + s_row8;
                src = Bb + ((size_t)(n0 + row) * K + t * 64) * 2 + s_col16 * 16;
            }
            __builtin_amdgcn_global_load_lds(
                (const __attribute__((address_space(1))) void*)src,
                (__attribute__((address_space(3))) void*)(smem + c * 1024), 16, 0, 0);
        }
        __syncthreads();   // drains vmcnt(0): tile resident

#pragma unroll
        for (int kk = 0; kk < 2; ++kk) {
            bf16x8 af[4], bf[4];
#pragma unroll
            for (int mi = 0; mi < 4; ++mi)
                af[mi] = *(const bf16x8*)(smem + (wm0 + mi * 16 + lr) * 128 + kk * 64 + lg * 16);
#pragma unroll
            for (int ni = 0; ni < 4; ++ni)
                bf[ni] = *(const bf16x8*)(smem + 32768 + (wn0 + ni * 16 + lr) * 128 + kk * 64 + lg * 16);
            __builtin_amdgcn_s_setprio(1);
#pragma unroll
            for (int mi = 0; mi < 4; ++mi)
#pragma unroll
                for (int ni = 0; ni < 4; ++ni)
                    acc[mi][ni] = __builtin_amdgcn_mfma_f32_16x16x32_bf16(
                        af[mi], bf[ni], acc[mi][ni], 0, 0, 0);
            __builtin_amdgcn_s_setprio(0);
        }
        __syncthreads();   // all reads done before next stage overwrites
    }

    // epilogue: D layout col = lane&15 (n), row = (lane>>4)*4 + r (m)
#pragma unroll
    for (int mi = 0; mi < 4; ++mi)
#pragma unroll
        for (int ni = 0; ni < 4; ++ni)
#pragma unroll
            for (int r = 0; r < 4; ++r) {
                int m = m0 + wm0 + mi * 16 + lg * 4 + r;
                int n = n0 + wn0 + ni * 16 + lr;
                float v = acc[mi][ni][r];
                if (MODE == 0) {
                    int proj = n >> 10, nn = n & 1023;
                    int h = nn >> 6, d = nn & 63;
                    int bb = m >> 11, c = m & 2047;
                    if (proj == 2) {
                        // Vt layout: [bh][d][2048]
                        ((__bf16*)Out)[(size_t)2 * 8388608 +
                                       ((size_t)((bb * 16 + h) * 64 + d)) * 2048 + c] = (__bf16)v;
                    } else {
                        float scale = (proj == 0) ? 0.125f : 1.0f;
                        ((__bf16*)Out)[(size_t)proj * 8388608 +
                                       ((size_t)(bb * 16 + h) * 2048 + c) * 64 + d] =
                            (__bf16)(v * scale);
                    }
                } else {
                    ((float*)Out)[(size_t)m * N + n] = v;
                }
            }
}

// ---------------------------------------------------------------------------
// Flash attention (causal), swapped-QK^T structure (r2-proven, unchanged).
// ---------------------------------------------------------------------------
__device__ __forceinline__ unsigned swz(unsigned d) {
    return d ^ (((d >> 7) & 7) << 4);
}

__launch_bounds__(256, 4)
__global__ void attn_fwd(const __bf16* __restrict__ Q, const __bf16* __restrict__ K,
                         const __bf16* __restrict__ Vt, __bf16* __restrict__ Aout) {
    __shared__ char smem[40960];
    const int id = blockIdx.x;
    const int vid = (id & 7) * 128 + (id >> 3);
    const int bh = vid >> 4, pr = vid & 15;
    const int w = threadIdx.x >> 6, lane = threadIdx.x & 63;
    const int lr = lane & 15, lg = lane >> 4;
    const char* Kb  = (const char*)(K  + (size_t)bh * 2048 * 64);
    const char* Vtb = (const char*)(Vt + (size_t)bh * 64 * 2048);
    const __bf16* Qb = Q + (size_t)bh * 2048 * 64;
    const int b = bh >> 4, h = bh & 15;
    char* Pb = smem + 32768 + w * 2048;

    for (int pass = 0; pass < 2; ++pass) {
        const int qt = pass ? pr : 31 - pr;
        const int q0 = qt * 64 + w * 16;
        const int nt = qt + 1;

        bf16x8 qf[2];
#pragma unroll
        for (int kk = 0; kk < 2; ++kk)
            qf[kk] = *(const bf16x8*)&Qb[(size_t)(q0 + lr) * 64 + kk * 32 + lg * 8];

        f32x4 o[4] = {};
        float m = NEG_INF, l = 0.f;

        __syncthreads();
        {
            char* kd = smem;
            char* vd = smem + 16384;
#pragma unroll
            for (int i = 0; i < 2; ++i) {
                unsigned c = (unsigned)(w * 2 + i);
                unsigned d = c * 1024 + (unsigned)lane * 16;
                unsigned bs = swz(d);
                __builtin_amdgcn_global_load_lds(
                    (const __attribute__((address_space(1))) void*)(Kb + bs),
                    (__attribute__((address_space(3))) void*)(kd + c * 1024), 16, 0, 0);
                unsigned row = bs >> 7, colb = bs & 127;
                __builtin_amdgcn_global_load_lds(
                    (const __attribute__((address_space(1))) void*)(Vtb + (size_t)row * 4096 + colb),
                    (__attribute__((address_space(3))) void*)(vd + c * 1024), 16, 0, 0);
            }
        }

        for (int t = 0; t < nt; ++t) {
            __syncthreads();
            if (t + 1 < nt) {
                char* kd = smem + ((t + 1) & 1) * 8192;
                char* vd = smem + 16384 + ((t + 1) & 1) * 8192;
#pragma unroll
                for (int i = 0; i < 2; ++i) {
                    unsigned c = (unsigned)(w * 2 + i);
                    unsigned d = c * 1024 + (unsigned)lane * 16;
                    unsigned bs = swz(d);
                    __builtin_amdgcn_global_load_lds(
                        (const __attribute__((address_space(1))) void*)(Kb + (size_t)(t + 1) * 8192 + bs),
                        (__attribute__((address_space(3))) void*)(kd + c * 1024), 16, 0, 0);
                    unsigned row = bs >> 7, colb = bs & 127;
                    __builtin_amdgcn_global_load_lds(
                        (const __attribute__((address_space(1))) void*)(Vtb + (size_t)row * 4096 +
                                                                       (size_t)(t + 1) * 128 + colb),
                        (__attribute__((address_space(3))) void*)(vd + c * 1024), 16, 0, 0);
                }
            }
            const char* Ks = smem + (t & 1) * 8192;
            const char* Vs = smem + 16384 + (t & 1) * 8192;
            const int k0 = t * 64;

            f32x4 s[4] = {};
#pragma unroll
            for (int kk = 0; kk < 2; ++kk)
#pragma unroll
                for (int sub = 0; sub < 4; ++sub) {
                    bf16x8 kf = *(const bf16x8*)(Ks + swz((unsigned)((sub * 16 + lr) * 128 + kk * 64 + lg * 16)));
                    s[sub] = __builtin_amdgcn_mfma_f32_16x16x32_bf16(kf, qf[kk], s[sub], 0, 0, 0);
                }
            if (t == qt) {
#pragma unroll
                for (int sub = 0; sub < 4; ++sub)
#pragma unroll
                    for (int r = 0; r < 4; ++r)
                        if (k0 + sub * 16 + lg * 4 + r > q0 + lr) s[sub][r] = NEG_INF;
            }
            float mloc = NEG_INF;
#pragma unroll
            for (int sub = 0; sub < 4; ++sub)
#pragma unroll
                for (int r = 0; r < 4; ++r) mloc = fmaxf(mloc, s[sub][r]);
            mloc = fmaxf(mloc, __shfl_xor(mloc, 16));
            mloc = fmaxf(mloc, __shfl_xor(mloc, 32));
            float mnew = fmaxf(m, mloc);
            float alpha = __expf(m - mnew);
            float rs = 0.f;
#pragma unroll
            for (int sub = 0; sub < 4; ++sub)
#pragma unroll
                for (int r = 0; r < 4; ++r) {
                    float p = __expf(s[sub][r] - mnew);
                    s[sub][r] = p;
                    rs += p;
                }
            rs += __shfl_xor(rs, 16);
            rs += __shfl_xor(rs, 32);
            l = l * alpha + rs;
            m = mnew;
#pragma unroll
            for (int ni = 0; ni < 4; ++ni) o[ni] *= alpha;

#pragma unroll
            for (int sub = 0; sub < 4; ++sub) {
                bf16x4 pk;
#pragma unroll
                for (int r = 0; r < 4; ++r) pk[r] = (__bf16)s[sub][r];
                *(bf16x4*)(Pb + swz((unsigned)(lr * 128 + sub * 32 + lg * 8))) = pk;
            }
            bf16x8 pfr[2];
#pragma unroll
            for (int kk = 0; kk < 2; ++kk)
                pfr[kk] = *(const bf16x8*)(Pb + swz((unsigned)(lr * 128 + kk * 64 + lg * 16)));

#pragma unroll
            for (int kk = 0; kk < 2; ++kk)
#pragma unroll
                for (int ni = 0; ni < 4; ++ni) {
                    bf16x8 vf = *(const bf16x8*)(Vs + swz((unsigned)((ni * 16 + lr) * 128 + kk * 64 + lg * 16)));
                    o[ni] = __builtin_amdgcn_mfma_f32_16x16x32_bf16(vf, pfr[kk], o[ni], 0, 0, 0);
                }
        }

        float rinv = 1.0f / l;
#pragma unroll
        for (int ni = 0; ni < 4; ++ni) {
            bf16x4 ov;
#pragma unroll
            for (int r = 0; r < 4; ++r) ov[r] = (__bf16)(o[ni][r] * rinv);
            *(bf16x4*)&Aout[((size_t)b * 2048 + q0 + lr) * 1024 + h * 64 + ni * 16 + lg * 4] = ov;
        }
    }
}

// ---------------------------------------------------------------------------
// launch
// ---------------------------------------------------------------------------
extern "C" void kernel_launch(void* const* d_in, const int* in_sizes, int n_in,
                              void* d_out, int out_size, void* d_ws, size_t ws_size,
                              hipStream_t stream) {
    const float* x  = (const float*)d_in[0];
    const float* Wk = (const float*)d_in[1];   // dict order: x, Wk, Wq, Wv, Wo
    const float* Wq = (const float*)d_in[2];
    const float* Wv = (const float*)d_in[3];
    const float* Wo = (const float*)d_in[4];

    char* ws = (char*)d_ws;
    __bf16* xb   = (__bf16*)(ws);                 // [8192][1024]        16 MB
    __bf16* wqkv = (__bf16*)(ws + 16777216);      // [3072][1024]         6 MB
    __bf16* wo_b = (__bf16*)(ws + 23068672);      // [1024][1024]         2 MB
    __bf16* qkv  = (__bf16*)(ws + 25165824);      // Q,K: [64][2048][64]; Vt: [64][64][2048]
    __bf16* aout = (__bf16*)(ws + 75497472);      // [8192][1024]        16 MB
    float* out = (float*)d_out;

    cvt_f32_bf16<<<2048, 256, 0, stream>>>(x, xb, 8388608);
    cvt_weights<<<4096, 256, 0, stream>>>(Wq, Wk, Wv, Wo, wqkv, wo_b);

    gemm256<0><<<dim3(768), 512, 0, stream>>>(xb, wqkv, qkv, 8192, 3072, 1024);
    attn_fwd<<<dim3(1024), 256, 0, stream>>>(qkv, qkv + 8388608, qkv + 16777216, aout);
    gemm256<1><<<dim3(256), 512, 0, stream>>>(aout, wo_b, out, 8192, 1024, 1024);
}

// Round 9
// 193.213 us; speedup vs baseline: 3.2409x; 1.1298x over previous
//
#include <hip/hip_runtime.h>
#include <hip/hip_bf16.h>

typedef __bf16 bf16x8 __attribute__((ext_vector_type(8)));
typedef __bf16 bf16x4 __attribute__((ext_vector_type(4)));
typedef float f32x4 __attribute__((ext_vector_type(4)));

#define NEG_INF (-__builtin_inff())

// ---------------------------------------------------------------------------
// f32 -> bf16 conversion for x (vectorized, grid-stride)
// ---------------------------------------------------------------------------
__global__ void cvt_f32_bf16(const float* __restrict__ src, __bf16* __restrict__ dst, int n) {
    int idx = blockIdx.x * blockDim.x + threadIdx.x;
    int stride = gridDim.x * blockDim.x;
    for (int i = idx * 4; i < n; i += stride * 4) {
        float4 v = *(const float4*)(src + i);
        bf16x4 o;
        o[0] = (__bf16)v.x; o[1] = (__bf16)v.y; o[2] = (__bf16)v.z; o[3] = (__bf16)v.w;
        *(bf16x4*)(dst + i) = o;
    }
}

// ---------------------------------------------------------------------------
// All four weight matrices (1M elements each) in ONE launch.
// Wq,Wk,Wv -> wqkv (contiguous, proj order Q,K,V); Wo -> wo_b.
// ---------------------------------------------------------------------------
__global__ void cvt_weights(const float* __restrict__ Wq, const float* __restrict__ Wk,
                            const float* __restrict__ Wv, const float* __restrict__ Wo,
                            __bf16* __restrict__ wqkv, __bf16* __restrict__ wo_b) {
    int i = (blockIdx.x * blockDim.x + threadIdx.x) * 4;
    int sel = i >> 20;            // 0..3
    int off = i & 1048575;
    const float* src = (sel == 0) ? Wq : (sel == 1) ? Wk : (sel == 2) ? Wv : Wo;
    __bf16* dst = (sel < 3) ? (wqkv + (size_t)sel * 1048576) : wo_b;
    float4 v = *(const float4*)(src + off);
    bf16x4 o;
    o[0] = (__bf16)v.x; o[1] = (__bf16)v.y; o[2] = (__bf16)v.z; o[3] = (__bf16)v.w;
    *(bf16x4*)(dst + off) = o;
}

// ---------------------------------------------------------------------------
// Double-buffered 128x128 GEMM, BK=64, 256 threads (4 waves 2x2).
// LDS 64KB = 2 x (A 16KB | B 16KB). Per K-step: ONE __syncthreads (implicit
// vmcnt(0)+lgkmcnt(0)), then issue global_load_lds for t+1 into the other
// buffer, then ds_read+MFMA tile t while those loads fly (attn-proven
// pattern; the next loop-top barrier drains them after a full compute phase).
// out[m][n] = sum_k A[m][k]*B[n][k]  (A:[M][K], B:[N][K], bf16).
// MODE 0: bf16 out scattered to QKV layout; Q scaled 1/8; V transposed.
// MODE 1: f32 out row-major [M][N].
// ---------------------------------------------------------------------------
template <int MODE>
__launch_bounds__(256, 2)
__global__ void gemm_db(const __bf16* __restrict__ A, const __bf16* __restrict__ Bm,
                        void* __restrict__ Out, int M, int N, int K) {
    __shared__ __align__(1024) char smem[65536];   // buf b at b*32768: A 16KB | B 16KB
    const int tid = threadIdx.x;
    const int w = tid >> 6, lane = tid & 63;
    const int lr = lane & 15, lg = lane >> 4;
    const int wm0 = (w >> 1) * 64, wn0 = (w & 1) * 64;

    // bijective XCD swizzle (nwg % 8 == 0 for both call sites)
    const int nbx = gridDim.x;
    int id = blockIdx.y * nbx + blockIdx.x;
    int q8 = (nbx * gridDim.y) >> 3;
    int vid = (id & 7) * q8 + (id >> 3);
    const int m0 = (vid / nbx) * 128, n0 = (vid % nbx) * 128;

    const char* Ab = (const char*)A;
    const char* Bb = (const char*)Bm;

    f32x4 acc[4][4] = {};
    const int s_row8 = lane >> 3;   // 0..7
    const int s_col16 = lane & 7;   // 0..7

    // stage K-tile t into buffer `buf` (8 gload_lds per thread-quad pattern)
    auto stage = [&](int t, int buf) {
        char* base = smem + buf * 32768;
#pragma unroll
        for (int r = 0; r < 4; ++r) {
            int c = w * 4 + r;                       // wave-uniform chunk 0..15
            int row = c * 8 + s_row8;
            const char* srcA = Ab + ((size_t)(m0 + row) * K + t * 64) * 2 + s_col16 * 16;
            const char* srcB = Bb + ((size_t)(n0 + row) * K + t * 64) * 2 + s_col16 * 16;
            __builtin_amdgcn_global_load_lds(
                (const __attribute__((address_space(1))) void*)srcA,
                (__attribute__((address_space(3))) void*)(base + c * 1024), 16, 0, 0);
            __builtin_amdgcn_global_load_lds(
                (const __attribute__((address_space(1))) void*)srcB,
                (__attribute__((address_space(3))) void*)(base + 16384 + c * 1024), 16, 0, 0);
        }
    };

    const int nt = K >> 6;
    stage(0, 0);
    for (int t = 0; t < nt; ++t) {
        __syncthreads();   // drains vmcnt(0): tile t resident; lgkmcnt(0): buf[(t+1)&1] reads done
        if (t + 1 < nt) stage(t + 1, (t + 1) & 1);   // flies under compute of t
        const char* base = smem + (t & 1) * 32768;
#pragma unroll
        for (int kk = 0; kk < 2; ++kk) {
            bf16x8 af[4], bf[4];
#pragma unroll
            for (int mi = 0; mi < 4; ++mi)
                af[mi] = *(const bf16x8*)(base + (wm0 + mi * 16 + lr) * 128 + kk * 64 + lg * 16);
#pragma unroll
            for (int ni = 0; ni < 4; ++ni)
                bf[ni] = *(const bf16x8*)(base + 16384 + (wn0 + ni * 16 + lr) * 128 + kk * 64 + lg * 16);
            __builtin_amdgcn_s_setprio(1);
#pragma unroll
            for (int mi = 0; mi < 4; ++mi)
#pragma unroll
                for (int ni = 0; ni < 4; ++ni)
                    acc[mi][ni] = __builtin_amdgcn_mfma_f32_16x16x32_bf16(
                        af[mi], bf[ni], acc[mi][ni], 0, 0, 0);
            __builtin_amdgcn_s_setprio(0);
        }
    }

    // epilogue: D layout col = lane&15 (n), row = (lane>>4)*4 + r (m)
#pragma unroll
    for (int mi = 0; mi < 4; ++mi)
#pragma unroll
        for (int ni = 0; ni < 4; ++ni)
#pragma unroll
            for (int r = 0; r < 4; ++r) {
                int m = m0 + wm0 + mi * 16 + lg * 4 + r;
                int n = n0 + wn0 + ni * 16 + lr;
                float v = acc[mi][ni][r];
                if (MODE == 0) {
                    int proj = n >> 10, nn = n & 1023;
                    int h = nn >> 6, d = nn & 63;
                    int bb = m >> 11, c = m & 2047;
                    if (proj == 2) {
                        // Vt layout: [bh][d][2048]
                        ((__bf16*)Out)[(size_t)2 * 8388608 +
                                       ((size_t)((bb * 16 + h) * 64 + d)) * 2048 + c] = (__bf16)v;
                    } else {
                        float scale = (proj == 0) ? 0.125f : 1.0f;
                        ((__bf16*)Out)[(size_t)proj * 8388608 +
                                       ((size_t)(bb * 16 + h) * 2048 + c) * 64 + d] =
                            (__bf16)(v * scale);
                    }
                } else {
                    ((float*)Out)[(size_t)m * N + n] = v;
                }
            }
}

// ---------------------------------------------------------------------------
// Flash attention (causal), swapped-QK^T structure (r2-proven, unchanged).
// ---------------------------------------------------------------------------
__device__ __forceinline__ unsigned swz(unsigned d) {
    return d ^ (((d >> 7) & 7) << 4);
}

__launch_bounds__(256, 4)
__global__ void attn_fwd(const __bf16* __restrict__ Q, const __bf16* __restrict__ K,
                         const __bf16* __restrict__ Vt, __bf16* __restrict__ Aout) {
    __shared__ char smem[40960];
    const int id = blockIdx.x;
    const int vid = (id & 7) * 128 + (id >> 3);
    const int bh = vid >> 4, pr = vid & 15;
    const int w = threadIdx.x >> 6, lane = threadIdx.x & 63;
    const int lr = lane & 15, lg = lane >> 4;
    const char* Kb  = (const char*)(K  + (size_t)bh * 2048 * 64);
    const char* Vtb = (const char*)(Vt + (size_t)bh * 64 * 2048);
    const __bf16* Qb = Q + (size_t)bh * 2048 * 64;
    const int b = bh >> 4, h = bh & 15;
    char* Pb = smem + 32768 + w * 2048;

    for (int pass = 0; pass < 2; ++pass) {
        const int qt = pass ? pr : 31 - pr;
        const int q0 = qt * 64 + w * 16;
        const int nt = qt + 1;

        bf16x8 qf[2];
#pragma unroll
        for (int kk = 0; kk < 2; ++kk)
            qf[kk] = *(const bf16x8*)&Qb[(size_t)(q0 + lr) * 64 + kk * 32 + lg * 8];

        f32x4 o[4] = {};
        float m = NEG_INF, l = 0.f;

        __syncthreads();
        {
            char* kd = smem;
            char* vd = smem + 16384;
#pragma unroll
            for (int i = 0; i < 2; ++i) {
                unsigned c = (unsigned)(w * 2 + i);
                unsigned d = c * 1024 + (unsigned)lane * 16;
                unsigned bs = swz(d);
                __builtin_amdgcn_global_load_lds(
                    (const __attribute__((address_space(1))) void*)(Kb + bs),
                    (__attribute__((address_space(3))) void*)(kd + c * 1024), 16, 0, 0);
                unsigned row = bs >> 7, colb = bs & 127;
                __builtin_amdgcn_global_load_lds(
                    (const __attribute__((address_space(1))) void*)(Vtb + (size_t)row * 4096 + colb),
                    (__attribute__((address_space(3))) void*)(vd + c * 1024), 16, 0, 0);
            }
        }

        for (int t = 0; t < nt; ++t) {
            __syncthreads();
            if (t + 1 < nt) {
                char* kd = smem + ((t + 1) & 1) * 8192;
                char* vd = smem + 16384 + ((t + 1) & 1) * 8192;
#pragma unroll
                for (int i = 0; i < 2; ++i) {
                    unsigned c = (unsigned)(w * 2 + i);
                    unsigned d = c * 1024 + (unsigned)lane * 16;
                    unsigned bs = swz(d);
                    __builtin_amdgcn_global_load_lds(
                        (const __attribute__((address_space(1))) void*)(Kb + (size_t)(t + 1) * 8192 + bs),
                        (__attribute__((address_space(3))) void*)(kd + c * 1024), 16, 0, 0);
                    unsigned row = bs >> 7, colb = bs & 127;
                    __builtin_amdgcn_global_load_lds(
                        (const __attribute__((address_space(1))) void*)(Vtb + (size_t)row * 4096 +
                                                                       (size_t)(t + 1) * 128 + colb),
                        (__attribute__((address_space(3))) void*)(vd + c * 1024), 16, 0, 0);
                }
            }
            const char* Ks = smem + (t & 1) * 8192;
            const char* Vs = smem + 16384 + (t & 1) * 8192;
            const int k0 = t * 64;

            f32x4 s[4] = {};
#pragma unroll
            for (int kk = 0; kk < 2; ++kk)
#pragma unroll
                for (int sub = 0; sub < 4; ++sub) {
                    bf16x8 kf = *(const bf16x8*)(Ks + swz((unsigned)((sub * 16 + lr) * 128 + kk * 64 + lg * 16)));
                    s[sub] = __builtin_amdgcn_mfma_f32_16x16x32_bf16(kf, qf[kk], s[sub], 0, 0, 0);
                }
            if (t == qt) {
#pragma unroll
                for (int sub = 0; sub < 4; ++sub)
#pragma unroll
                    for (int r = 0; r < 4; ++r)
                        if (k0 + sub * 16 + lg * 4 + r > q0 + lr) s[sub][r] = NEG_INF;
            }
            float mloc = NEG_INF;
#pragma unroll
            for (int sub = 0; sub < 4; ++sub)
#pragma unroll
                for (int r = 0; r < 4; ++r) mloc = fmaxf(mloc, s[sub][r]);
            mloc = fmaxf(mloc, __shfl_xor(mloc, 16));
            mloc = fmaxf(mloc, __shfl_xor(mloc, 32));
            float mnew = fmaxf(m, mloc);
            float alpha = __expf(m - mnew);
            float rs = 0.f;
#pragma unroll
            for (int sub = 0; sub < 4; ++sub)
#pragma unroll
                for (int r = 0; r < 4; ++r) {
                    float p = __expf(s[sub][r] - mnew);
                    s[sub][r] = p;
                    rs += p;
                }
            rs += __shfl_xor(rs, 16);
            rs += __shfl_xor(rs, 32);
            l = l * alpha + rs;
            m = mnew;
#pragma unroll
            for (int ni = 0; ni < 4; ++ni) o[ni] *= alpha;

#pragma unroll
            for (int sub = 0; sub < 4; ++sub) {
                bf16x4 pk;
#pragma unroll
                for (int r = 0; r < 4; ++r) pk[r] = (__bf16)s[sub][r];
                *(bf16x4*)(Pb + swz((unsigned)(lr * 128 + sub * 32 + lg * 8))) = pk;
            }
            bf16x8 pfr[2];
#pragma unroll
            for (int kk = 0; kk < 2; ++kk)
                pfr[kk] = *(const bf16x8*)(Pb + swz((unsigned)(lr * 128 + kk * 64 + lg * 16)));

#pragma unroll
            for (int kk = 0; kk < 2; ++kk)
#pragma unroll
                for (int ni = 0; ni < 4; ++ni) {
                    bf16x8 vf = *(const bf16x8*)(Vs + swz((unsigned)((ni * 16 + lr) * 128 + kk * 64 + lg * 16)));
                    o[ni] = __builtin_amdgcn_mfma_f32_16x16x32_bf16(vf, pfr[kk], o[ni], 0, 0, 0);
                }
        }

        float rinv = 1.0f / l;
#pragma unroll
        for (int ni = 0; ni < 4; ++ni) {
            bf16x4 ov;
#pragma unroll
            for (int r = 0; r < 4; ++r) ov[r] = (__bf16)(o[ni][r] * rinv);
            *(bf16x4*)&Aout[((size_t)b * 2048 + q0 + lr) * 1024 + h * 64 + ni * 16 + lg * 4] = ov;
        }
    }
}

// ---------------------------------------------------------------------------
// launch
// ---------------------------------------------------------------------------
extern "C" void kernel_launch(void* const* d_in, const int* in_sizes, int n_in,
                              void* d_out, int out_size, void* d_ws, size_t ws_size,
                              hipStream_t stream) {
    const float* x  = (const float*)d_in[0];
    const float* Wk = (const float*)d_in[1];   // dict order: x, Wk, Wq, Wv, Wo
    const float* Wq = (const float*)d_in[2];
    const float* Wv = (const float*)d_in[3];
    const float* Wo = (const float*)d_in[4];

    char* ws = (char*)d_ws;
    __bf16* xb   = (__bf16*)(ws);                 // [8192][1024]        16 MB
    __bf16* wqkv = (__bf16*)(ws + 16777216);      // [3072][1024]         6 MB
    __bf16* wo_b = (__bf16*)(ws + 23068672);      // [1024][1024]         2 MB
    __bf16* qkv  = (__bf16*)(ws + 25165824);      // Q,K: [64][2048][64]; Vt: [64][64][2048]
    __bf16* aout = (__bf16*)(ws + 75497472);      // [8192][1024]        16 MB
    float* out = (float*)d_out;

    cvt_f32_bf16<<<2048, 256, 0, stream>>>(x, xb, 8388608);
    cvt_weights<<<4096, 256, 0, stream>>>(Wq, Wk, Wv, Wo, wqkv, wo_b);

    gemm_db<0><<<dim3(24, 64), 256, 0, stream>>>(xb, wqkv, qkv, 8192, 3072, 1024);
    attn_fwd<<<dim3(1024), 256, 0, stream>>>(qkv, qkv + 8388608, qkv + 16777216, aout);
    gemm_db<1><<<dim3(8, 64), 256, 0, stream>>>(aout, wo_b, out, 8192, 1024, 1024);
}

// Round 10
// 187.466 us; speedup vs baseline: 3.3403x; 1.0307x over previous
//
#include <hip/hip_runtime.h>
#include <hip/hip_bf16.h>

typedef __bf16 bf16x8 __attribute__((ext_vector_type(8)));
typedef __bf16 bf16x4 __attribute__((ext_vector_type(4)));
typedef float f32x4 __attribute__((ext_vector_type(4)));

#define NEG_INF (-__builtin_inff())

// ---------------------------------------------------------------------------
// ALL f32->bf16 conversions in ONE launch: x (8.4M) + Wq/Wk/Wv -> wqkv + Wo.
// 12582912 elements, 4/thread, grid 12288 x 256.
// ---------------------------------------------------------------------------
__global__ void cvt_all(const float* __restrict__ x,
                        const float* __restrict__ Wq, const float* __restrict__ Wk,
                        const float* __restrict__ Wv, const float* __restrict__ Wo,
                        __bf16* __restrict__ xb, __bf16* __restrict__ wqkv,
                        __bf16* __restrict__ wo_b) {
    int i = (blockIdx.x * blockDim.x + threadIdx.x) * 4;
    const float* src;
    __bf16* dst;
    int off;
    if (i < 8388608) {
        src = x; dst = xb; off = i;
    } else {
        int j = i - 8388608;
        int sel = j >> 20;            // 0..3
        off = j & 1048575;
        src = (sel == 0) ? Wq : (sel == 1) ? Wk : (sel == 2) ? Wv : Wo;
        dst = (sel < 3) ? (wqkv + (size_t)sel * 1048576) : wo_b;
    }
    float4 v = *(const float4*)(src + off);
    bf16x4 o;
    o[0] = (__bf16)v.x; o[1] = (__bf16)v.y; o[2] = (__bf16)v.z; o[3] = (__bf16)v.w;
    *(bf16x4*)(dst + off) = o;
}

// ---------------------------------------------------------------------------
// m97-structure GEMM (r4-proven, 87us QKV): 128x128 tile, BK=64, 256 threads
// (4 waves 2x2), SINGLE-buffer linear LDS 32KB, global_load_lds width=16,
// 2 x __syncthreads per K-step.
// out[m][n] = sum_k A[m][k]*B[n][k]  (A:[M][K], B:[N][K], bf16).
// MODE 0: bf16 out scattered to QKV layout; Q scaled 1/8; V transposed.
// MODE 1: f32 out row-major [M][N].
// ---------------------------------------------------------------------------
template <int MODE>
__launch_bounds__(256, 3)
__global__ void gemm_bt(const __bf16* __restrict__ A, const __bf16* __restrict__ Bm,
                        void* __restrict__ Out, int M, int N, int K) {
    __shared__ __align__(1024) char smem[32768];   // As [128][64] | Bs [128][64]
    const int tid = threadIdx.x;
    const int w = tid >> 6, lane = tid & 63;
    const int lr = lane & 15, lg = lane >> 4;
    const int wm0 = (w >> 1) * 64, wn0 = (w & 1) * 64;

    // bijective XCD swizzle (nwg % 8 == 0 for both call sites)
    const int nbx = gridDim.x;
    int id = blockIdx.y * nbx + blockIdx.x;
    int q8 = (nbx * gridDim.y) >> 3;
    int vid = (id & 7) * q8 + (id >> 3);
    const int m0 = (vid / nbx) * 128, n0 = (vid % nbx) * 128;

    const char* Ab = (const char*)A;
    const char* Bb = (const char*)Bm;

    f32x4 acc[4][4] = {};

    const int s_row8 = lane >> 3;   // 0..7
    const int s_col16 = lane & 7;   // 0..7

    const int nt = K >> 6;
    for (int t = 0; t < nt; ++t) {
#pragma unroll
        for (int r = 0; r < 4; ++r) {
            int c = w * 4 + r;                       // wave-uniform chunk 0..15
            int row = c * 8 + s_row8;
            const char* srcA = Ab + ((size_t)(m0 + row) * K + t * 64) * 2 + s_col16 * 16;
            const char* srcB = Bb + ((size_t)(n0 + row) * K + t * 64) * 2 + s_col16 * 16;
            __builtin_amdgcn_global_load_lds(
                (const __attribute__((address_space(1))) void*)srcA,
                (__attribute__((address_space(3))) void*)(smem + c * 1024), 16, 0, 0);
            __builtin_amdgcn_global_load_lds(
                (const __attribute__((address_space(1))) void*)srcB,
                (__attribute__((address_space(3))) void*)(smem + 16384 + c * 1024), 16, 0, 0);
        }
        __syncthreads();   // drains vmcnt(0): tile resident

#pragma unroll
        for (int kk = 0; kk < 2; ++kk) {
            bf16x8 af[4], bf[4];
#pragma unroll
            for (int mi = 0; mi < 4; ++mi)
                af[mi] = *(const bf16x8*)(smem + (wm0 + mi * 16 + lr) * 128 + kk * 64 + lg * 16);
#pragma unroll
            for (int ni = 0; ni < 4; ++ni)
                bf[ni] = *(const bf16x8*)(smem + 16384 + (wn0 + ni * 16 + lr) * 128 + kk * 64 + lg * 16);
            __builtin_amdgcn_s_setprio(1);
#pragma unroll
            for (int mi = 0; mi < 4; ++mi)
#pragma unroll
                for (int ni = 0; ni < 4; ++ni)
                    acc[mi][ni] = __builtin_amdgcn_mfma_f32_16x16x32_bf16(
                        af[mi], bf[ni], acc[mi][ni], 0, 0, 0);
            __builtin_amdgcn_s_setprio(0);
        }
        __syncthreads();   // all reads done before next stage overwrites
    }

    // epilogue: D layout col = lane&15 (n), row = (lane>>4)*4 + r (m)
#pragma unroll
    for (int mi = 0; mi < 4; ++mi)
#pragma unroll
        for (int ni = 0; ni < 4; ++ni)
#pragma unroll
            for (int r = 0; r < 4; ++r) {
                int m = m0 + wm0 + mi * 16 + lg * 4 + r;
                int n = n0 + wn0 + ni * 16 + lr;
                float v = acc[mi][ni][r];
                if (MODE == 0) {
                    int proj = n >> 10, nn = n & 1023;
                    int h = nn >> 6, d = nn & 63;
                    int bb = m >> 11, c = m & 2047;
                    if (proj == 2) {
                        // Vt layout: [bh][d][2048]
                        ((__bf16*)Out)[(size_t)2 * 8388608 +
                                       ((size_t)((bb * 16 + h) * 64 + d)) * 2048 + c] = (__bf16)v;
                    } else {
                        float scale = (proj == 0) ? 0.125f : 1.0f;
                        ((__bf16*)Out)[(size_t)proj * 8388608 +
                                       ((size_t)(bb * 16 + h) * 2048 + c) * 64 + d] =
                            (__bf16)(v * scale);
                    }
                } else {
                    ((float*)Out)[(size_t)m * N + n] = v;
                }
            }
}

// ---------------------------------------------------------------------------
// Flash attention (causal), swapped-QK^T, MERGED passes: block (bh, pr)
// streams K/V tiles 0..qta ONCE, accumulating q-tile a (qta=31-pr) every
// tile and q-tile b (qtb=pr <= 15 < qta) while t <= qtb. Saves 26% of
// staging + loop iterations vs the two-pass version at identical math.
// ---------------------------------------------------------------------------
__device__ __forceinline__ unsigned swz(unsigned d) {
    return d ^ (((d >> 7) & 7) << 4);
}

__launch_bounds__(256, 4)
__global__ void attn_fwd(const __bf16* __restrict__ Q, const __bf16* __restrict__ K,
                         const __bf16* __restrict__ Vt, __bf16* __restrict__ Aout) {
    __shared__ char smem[40960];   // K dbuf 2x8KB | Vt dbuf 2x8KB | P 4x2KB
    const int id = blockIdx.x;
    const int vid = (id & 7) * 128 + (id >> 3);   // bijective XCD swizzle
    const int bh = vid >> 4, pr = vid & 15;
    const int w = threadIdx.x >> 6, lane = threadIdx.x & 63;
    const int lr = lane & 15, lg = lane >> 4;
    const char* Kb  = (const char*)(K  + (size_t)bh * 2048 * 64);
    const char* Vtb = (const char*)(Vt + (size_t)bh * 64 * 2048);
    const __bf16* Qb = Q + (size_t)bh * 2048 * 64;
    const int b = bh >> 4, h = bh & 15;
    char* Pb = smem + 32768 + w * 2048;

    const int qta = 31 - pr, qtb = pr;            // qta >= 16 > qtb
    const int q0a = qta * 64 + w * 16, q0b = qtb * 64 + w * 16;

    bf16x8 qfa[2], qfb[2];
#pragma unroll
    for (int kk = 0; kk < 2; ++kk) {
        qfa[kk] = *(const bf16x8*)&Qb[(size_t)(q0a + lr) * 64 + kk * 32 + lg * 8];
        qfb[kk] = *(const bf16x8*)&Qb[(size_t)(q0b + lr) * 64 + kk * 32 + lg * 8];
    }

    f32x4 oa[4] = {}, ob[4] = {};
    float ma = NEG_INF, la = 0.f, mb = NEG_INF, lb = 0.f;

    // prologue: stage tile 0 -> buf 0
    {
        char* kd = smem;
        char* vd = smem + 16384;
#pragma unroll
        for (int i = 0; i < 2; ++i) {
            unsigned c = (unsigned)(w * 2 + i);
            unsigned d = c * 1024 + (unsigned)lane * 16;
            unsigned bs = swz(d);
            __builtin_amdgcn_global_load_lds(
                (const __attribute__((address_space(1))) void*)(Kb + bs),
                (__attribute__((address_space(3))) void*)(kd + c * 1024), 16, 0, 0);
            unsigned row = bs >> 7, colb = bs & 127;
            __builtin_amdgcn_global_load_lds(
                (const __attribute__((address_space(1))) void*)(Vtb + (size_t)row * 4096 + colb),
                (__attribute__((address_space(3))) void*)(vd + c * 1024), 16, 0, 0);
        }
    }

    const int nt = qta + 1;
    for (int t = 0; t < nt; ++t) {
        __syncthreads();   // implicit vmcnt(0)+lgkmcnt(0): tile t resident, old reads done
        if (t + 1 < nt) {  // prefetch t+1 while computing t
            char* kd = smem + ((t + 1) & 1) * 8192;
            char* vd = smem + 16384 + ((t + 1) & 1) * 8192;
#pragma unroll
            for (int i = 0; i < 2; ++i) {
                unsigned c = (unsigned)(w * 2 + i);
                unsigned d = c * 1024 + (unsigned)lane * 16;
                unsigned bs = swz(d);
                __builtin_amdgcn_global_load_lds(
                    (const __attribute__((address_space(1))) void*)(Kb + (size_t)(t + 1) * 8192 + bs),
                    (__attribute__((address_space(3))) void*)(kd + c * 1024), 16, 0, 0);
                unsigned row = bs >> 7, colb = bs & 127;
                __builtin_amdgcn_global_load_lds(
                    (const __attribute__((address_space(1))) void*)(Vtb + (size_t)row * 4096 +
                                                                   (size_t)(t + 1) * 128 + colb),
                    (__attribute__((address_space(3))) void*)(vd + c * 1024), 16, 0, 0);
            }
        }
        const char* Ks = smem + (t & 1) * 8192;
        const char* Vs = smem + 16384 + (t & 1) * 8192;
        const int k0 = t * 64;

        // one q-tile's full per-tile body (QK^T -> online softmax -> PV)
        auto process = [&](const bf16x8 (&qf)[2], int q0, bool diag,
                           f32x4 (&o)[4], float& m, float& l) {
            f32x4 s[4] = {};
#pragma unroll
            for (int kk = 0; kk < 2; ++kk)
#pragma unroll
                for (int sub = 0; sub < 4; ++sub) {
                    bf16x8 kf = *(const bf16x8*)(Ks + swz((unsigned)((sub * 16 + lr) * 128 + kk * 64 + lg * 16)));
                    s[sub] = __builtin_amdgcn_mfma_f32_16x16x32_bf16(kf, qf[kk], s[sub], 0, 0, 0);
                }
            if (diag) {
#pragma unroll
                for (int sub = 0; sub < 4; ++sub)
#pragma unroll
                    for (int r = 0; r < 4; ++r)
                        if (k0 + sub * 16 + lg * 4 + r > q0 + lr) s[sub][r] = NEG_INF;
            }
            float mloc = NEG_INF;
#pragma unroll
            for (int sub = 0; sub < 4; ++sub)
#pragma unroll
                for (int r = 0; r < 4; ++r) mloc = fmaxf(mloc, s[sub][r]);
            mloc = fmaxf(mloc, __shfl_xor(mloc, 16));
            mloc = fmaxf(mloc, __shfl_xor(mloc, 32));
            float mnew = fmaxf(m, mloc);
            float alpha = __expf(m - mnew);
            float rs = 0.f;
#pragma unroll
            for (int sub = 0; sub < 4; ++sub)
#pragma unroll
                for (int r = 0; r < 4; ++r) {
                    float p = __expf(s[sub][r] - mnew);
                    s[sub][r] = p;
                    rs += p;
                }
            rs += __shfl_xor(rs, 16);
            rs += __shfl_xor(rs, 32);
            l = l * alpha + rs;
            m = mnew;
#pragma unroll
            for (int ni = 0; ni < 4; ++ni) o[ni] *= alpha;

#pragma unroll
            for (int sub = 0; sub < 4; ++sub) {
                bf16x4 pk;
#pragma unroll
                for (int r = 0; r < 4; ++r) pk[r] = (__bf16)s[sub][r];
                *(bf16x4*)(Pb + swz((unsigned)(lr * 128 + sub * 32 + lg * 8))) = pk;
            }
            bf16x8 pfr[2];
#pragma unroll
            for (int kk = 0; kk < 2; ++kk)
                pfr[kk] = *(const bf16x8*)(Pb + swz((unsigned)(lr * 128 + kk * 64 + lg * 16)));

#pragma unroll
            for (int kk = 0; kk < 2; ++kk)
#pragma unroll
                for (int ni = 0; ni < 4; ++ni) {
                    bf16x8 vf = *(const bf16x8*)(Vs + swz((unsigned)((ni * 16 + lr) * 128 + kk * 64 + lg * 16)));
                    o[ni] = __builtin_amdgcn_mfma_f32_16x16x32_bf16(vf, pfr[kk], o[ni], 0, 0, 0);
                }
        };

        process(qfa, q0a, t == qta, oa, ma, la);
        if (t <= qtb) process(qfb, q0b, t == qtb, ob, mb, lb);
    }

    // epilogue: Aout[b][c][h*64 + ni*16 + lg*4], vectorized 8B stores
    float ra = 1.0f / la, rb = 1.0f / lb;
#pragma unroll
    for (int ni = 0; ni < 4; ++ni) {
        bf16x4 va, vb;
#pragma unroll
        for (int r = 0; r < 4; ++r) {
            va[r] = (__bf16)(oa[ni][r] * ra);
            vb[r] = (__bf16)(ob[ni][r] * rb);
        }
        *(bf16x4*)&Aout[((size_t)b * 2048 + q0a + lr) * 1024 + h * 64 + ni * 16 + lg * 4] = va;
        *(bf16x4*)&Aout[((size_t)b * 2048 + q0b + lr) * 1024 + h * 64 + ni * 16 + lg * 4] = vb;
    }
}

// ---------------------------------------------------------------------------
// launch
// ---------------------------------------------------------------------------
extern "C" void kernel_launch(void* const* d_in, const int* in_sizes, int n_in,
                              void* d_out, int out_size, void* d_ws, size_t ws_size,
                              hipStream_t stream) {
    const float* x  = (const float*)d_in[0];
    const float* Wk = (const float*)d_in[1];   // dict order: x, Wk, Wq, Wv, Wo
    const float* Wq = (const float*)d_in[2];
    const float* Wv = (const float*)d_in[3];
    const float* Wo = (const float*)d_in[4];

    char* ws = (char*)d_ws;
    __bf16* xb   = (__bf16*)(ws);                 // [8192][1024]        16 MB
    __bf16* wqkv = (__bf16*)(ws + 16777216);      // [3072][1024]         6 MB
    __bf16* wo_b = (__bf16*)(ws + 23068672);      // [1024][1024]         2 MB
    __bf16* qkv  = (__bf16*)(ws + 25165824);      // Q,K: [64][2048][64]; Vt: [64][64][2048]
    __bf16* aout = (__bf16*)(ws + 75497472);      // [8192][1024]        16 MB
    float* out = (float*)d_out;

    cvt_all<<<12288, 256, 0, stream>>>(x, Wq, Wk, Wv, Wo, xb, wqkv, wo_b);

    gemm_bt<0><<<dim3(24, 64), 256, 0, stream>>>(xb, wqkv, qkv, 8192, 3072, 1024);
    attn_fwd<<<dim3(1024), 256, 0, stream>>>(qkv, qkv + 8388608, qkv + 16777216, aout);
    gemm_bt<1><<<dim3(8, 64), 256, 0, stream>>>(aout, wo_b, out, 8192, 1024, 1024);
}